// Round 6
// baseline (708.451 us; speedup 1.0000x reference)
//
#include <hip/hip_runtime.h>

// ---------------- Diagnostic marker: neither input mapping validated ----------------
__global__ void bad_map_marker(float* out) {
    if (threadIdx.x == 0 && blockIdx.x == 0) out[0] = 1.0e6f;
}

// ---------------- Tail (generic fallback only): LN1+ReLU -> L2 -> LN2+ReLU -> L3 ----------------
__device__ __forceinline__ void mlp_tail_compute(float* h, float* pr, int D,
        const float* g1, const float* be1,
        const float* W2, const float* b2,
        const float* g2, const float* be2,
        const float* W3, const float* b3) {
    float s = 0.f, ss = 0.f;
    #pragma unroll
    for (int d = 0; d < 64; ++d) { s += h[d]; ss += h[d] * h[d]; }
    float mu  = s * (1.f / 64.f);
    float inv = rsqrtf(ss * (1.f / 64.f) - mu * mu + 1e-5f);
    #pragma unroll
    for (int d = 0; d < 64; ++d)
        h[d] = fmaxf((h[d] - mu) * inv * g1[d] + be1[d], 0.f);

    float a2[32];
    const float4* w2v = (const float4*)W2;
    #pragma unroll
    for (int n = 0; n < 32; ++n) a2[n] = b2[n];
    for (int k = 0; k < 64; ++k) {
        float hk = h[k];
        #pragma unroll
        for (int q = 0; q < 8; ++q) {
            float4 w = w2v[k * 8 + q];
            a2[4 * q + 0] += hk * w.x;
            a2[4 * q + 1] += hk * w.y;
            a2[4 * q + 2] += hk * w.z;
            a2[4 * q + 3] += hk * w.w;
        }
    }
    s = 0.f; ss = 0.f;
    #pragma unroll
    for (int n = 0; n < 32; ++n) { s += a2[n]; ss += a2[n] * a2[n]; }
    mu  = s * (1.f / 32.f);
    inv = rsqrtf(ss * (1.f / 32.f) - mu * mu + 1e-5f);
    #pragma unroll
    for (int n = 0; n < 32; ++n)
        a2[n] = fmaxf((a2[n] - mu) * inv * g2[n] + be2[n], 0.f);

    for (int d = 0; d < D; ++d) pr[d] = b3[d];
    for (int k = 0; k < 32; ++k) {
        float hk = a2[k];
        const float* wr = W3 + k * D;
        for (int d = 0; d < D; ++d) pr[d] += hk * wr[d];
    }
}

// Coalesced diag-embed epilogue, 256 pairs/block -> 16384 float4 chunks. Plain stores.
__device__ __forceinline__ void store_diag16_f32_256(const float* pp, float* out, int P) {
    const int t = threadIdx.x;
    float4* outv = (float4*)out + (size_t)blockIdx.x * 16384;
    const int pbase = blockIdx.x * 256;
    #pragma unroll 8
    for (int it = 0; it < 64; ++it) {
        int g = it * 256 + t;
        int pl = g >> 6;
        int rem = g & 63;
        int d = rem >> 2;
        int c4 = rem & 3;
        float val = pp[pl * 17 + d];
        bool on = (d >> 2) == c4;
        float4 v;
        v.x = (on && (d & 3) == 0) ? val : 0.f;
        v.y = (on && (d & 3) == 1) ? val : 0.f;
        v.z = (on && (d & 3) == 2) ? val : 0.f;
        v.w = (on && (d & 3) == 3) ? val : 0.f;
        if (pbase + pl < P) outv[g] = v;
    }
}

// ---------------- Fast path stage 1 (F==128): tiled GEMM, Y[e][n] ----------------
// 32 edges x 128 cols per block -> 625 blocks (2.4/CU); thread: 2 edges x 8 cols.
// (R0's 64-edge tile gave only 313 blocks = 1.2 blocks/CU: half the CUs idle.)
__global__ __launch_bounds__(256)
void precompute_y(const float* __restrict__ ef, const float* __restrict__ W1,
                  const float* __restrict__ b1, float* __restrict__ Y, int E) {
    __shared__ __align__(16) float el[32 * 132];   // 16896 B
    const int t = threadIdx.x;
    const int ebase = blockIdx.x * 32;

    for (int idx = t; idx < 1024; idx += 256) {
        int er = idx >> 5, ec = idx & 31;
        if (ebase + er < E)
            *((float4*)(el + er * 132) + ec) =
                *((const float4*)(ef + (size_t)(ebase + er) * 128) + ec);
    }
    __syncthreads();

    const int cg = t & 15;
    const int eg = t >> 4;
    const int half = cg >> 3;
    const int col64 = (cg & 7) * 8;

    float acc[2][8];
    #pragma unroll
    for (int i = 0; i < 2; ++i)
        #pragma unroll
        for (int c = 0; c < 8; ++c) acc[i][c] = 0.f;

    const float* wbase = W1 + (size_t)half * 128 * 64 + col64;
    #pragma unroll 4
    for (int k = 0; k < 128; ++k) {
        float4 w0 = *(const float4*)(wbase + (size_t)k * 64);
        float4 w1 = *(const float4*)(wbase + (size_t)k * 64 + 4);
        float wv[8] = {w0.x, w0.y, w0.z, w0.w, w1.x, w1.y, w1.z, w1.w};
        #pragma unroll
        for (int i = 0; i < 2; ++i) {
            float a = el[(eg * 2 + i) * 132 + k];
            #pragma unroll
            for (int c = 0; c < 8; ++c) acc[i][c] += a * wv[c];
        }
    }

    float bb[8];
    #pragma unroll
    for (int c = 0; c < 8; ++c) bb[c] = (half == 0) ? b1[col64 + c] : 0.f;
    #pragma unroll
    for (int i = 0; i < 2; ++i) {
        int e = ebase + eg * 2 + i;
        if (e < E) {
            float* dst = Y + (size_t)e * 128 + half * 64 + col64;
            #pragma unroll
            for (int c = 0; c < 8; ++c) dst[c] = acc[i][c] + bb[c];
        }
    }
}

// ---------------- Fast path stage 2: 1 thread/pair, TWO-PASS streaming ----------------
// Occupancy fix v2 (R5's quad-split regressed: cross-lane cost > occupancy gain).
// Pass 1 streams the 512B gather accumulating LN1 stats (h discarded); pass 2
// re-reads the L1/L2-hot bytes, normalizes+ReLUs and FMAs straight into a2[32].
// Live state drops ~170 -> ~80 VGPR; __launch_bounds__(256,4) caps at 128 VGPR
// -> 4 waves/SIMD (2x latency hiding on the random Y gathers). The cap also
// forces the compiler to re-load in pass 2 instead of keeping 128 floats live.
__global__ __launch_bounds__(256, 4)
void sheaf_pairs(const int* __restrict__ pi, const int* __restrict__ pj,
                 const float* __restrict__ Y,
                 const float* __restrict__ g1, const float* __restrict__ be1,
                 const float* __restrict__ W2, const float* __restrict__ b2,
                 const float* __restrict__ g2, const float* __restrict__ be2,
                 const float* __restrict__ W3, const float* __restrict__ b3,
                 float* __restrict__ out, int P) {
    __shared__ float pp[256 * 17];
    __shared__ __align__(16) float w2s[64 * 32];
    __shared__ __align__(16) float w3s[32 * 16];
    __shared__ float g1s[64], be1s[64], b2s[32], g2s[32], be2s[32], b3s[16];

    const int t = threadIdx.x;

    // Stage all MLP-tail weights into LDS (once per block).
    {
        const float4* s2 = (const float4*)W2;      // 512 float4
        float4* d2 = (float4*)w2s;
        d2[t]       = s2[t];
        d2[t + 256] = s2[t + 256];
        if (t < 128) ((float4*)w3s)[t] = ((const float4*)W3)[t];   // 128 float4
        if (t < 64)                 { g1s[t] = g1[t]; be1s[t] = be1[t]; }
        else if (t < 96)            b2s[t - 64]   = b2[t - 64];
        else if (t < 128)           g2s[t - 96]   = g2[t - 96];
        else if (t < 160)           be2s[t - 128] = be2[t - 128];
        else if (t < 176)           b3s[t - 160]  = b3[t - 160];
    }

    int p = blockIdx.x * 256 + t;
    int pc = p < P ? p : P - 1;
    int i = pi[pc], j = pj[pc];
    const float4* y1 = (const float4*)(Y + (size_t)i * 128);
    const float4* y2 = (const float4*)(Y + (size_t)j * 128 + 64);

    // Pass 1: LN1 statistics only; h not kept.
    float s = 0.f, ss = 0.f;
    #pragma unroll
    for (int q = 0; q < 16; ++q) {
        float4 a = y1[q], b = y2[q];
        float h0 = a.x + b.x, h1 = a.y + b.y, h2 = a.z + b.z, h3 = a.w + b.w;
        s  += h0 + h1 + h2 + h3;
        ss += h0 * h0 + h1 * h1 + h2 * h2 + h3 * h3;
    }
    float mu  = s * (1.f / 64.f);
    float inv = rsqrtf(ss * (1.f / 64.f) - mu * mu + 1e-5f);

    __syncthreads();   // weights staged

    // Pass 2: re-read (cache-hot), normalize+ReLU, FMA into a2.
    float a2[32];
    #pragma unroll
    for (int n = 0; n < 32; ++n) a2[n] = b2s[n];
    #pragma unroll
    for (int q = 0; q < 16; ++q) {
        float4 a = y1[q], b = y2[q];
        float hh[4] = {a.x + b.x, a.y + b.y, a.z + b.z, a.w + b.w};
        #pragma unroll
        for (int c = 0; c < 4; ++c) {
            int k = 4 * q + c;
            float hk = fmaxf((hh[c] - mu) * inv * g1s[k] + be1s[k], 0.f);
            const float4* wr = (const float4*)(w2s + k * 32);
            #pragma unroll
            for (int u = 0; u < 8; ++u) {
                float4 w = wr[u];
                a2[4 * u + 0] += hk * w.x;
                a2[4 * u + 1] += hk * w.y;
                a2[4 * u + 2] += hk * w.z;
                a2[4 * u + 3] += hk * w.w;
            }
        }
    }

    // LN2 + ReLU.
    s = 0.f; ss = 0.f;
    #pragma unroll
    for (int n = 0; n < 32; ++n) { s += a2[n]; ss += a2[n] * a2[n]; }
    mu  = s * (1.f / 32.f);
    inv = rsqrtf(ss * (1.f / 32.f) - mu * mu + 1e-5f);
    #pragma unroll
    for (int n = 0; n < 32; ++n)
        a2[n] = fmaxf((a2[n] - mu) * inv * g2s[n] + be2s[n], 0.f);

    // Linear(32,16).
    float pr[16];
    #pragma unroll
    for (int d = 0; d < 16; ++d) pr[d] = b3s[d];
    #pragma unroll 8
    for (int k = 0; k < 32; ++k) {
        float hk = a2[k];
        #pragma unroll
        for (int u = 0; u < 4; ++u) {
            float4 w = *(const float4*)(w3s + k * 16 + u * 4);
            pr[4 * u + 0] += hk * w.x;
            pr[4 * u + 1] += hk * w.y;
            pr[4 * u + 2] += hk * w.z;
            pr[4 * u + 3] += hk * w.w;
        }
    }

    #pragma unroll
    for (int d = 0; d < 16; ++d) pp[t * 17 + d] = pr[d];
    __syncthreads();
    store_diag16_f32_256(pp, out, P);
}

// ---------------- Generic fallback: runtime F, D (<=32) ----------------
__global__ __launch_bounds__(256)
void sheaf_generic(const float* __restrict__ ef,
                   const int* __restrict__ pi, const int* __restrict__ pj,
                   const float* __restrict__ W1, const float* __restrict__ b1,
                   const float* __restrict__ g1, const float* __restrict__ be1,
                   const float* __restrict__ W2, const float* __restrict__ b2,
                   const float* __restrict__ g2, const float* __restrict__ be2,
                   const float* __restrict__ W3, const float* __restrict__ b3,
                   float* __restrict__ out, int P, int F, int D) {
    __shared__ float pp[256 * 17];
    int p = blockIdx.x * 256 + threadIdx.x;
    int pc = p < P ? p : P - 1;
    int i = pi[pc], j = pj[pc];
    const float* efi = ef + (size_t)i * F;
    const float* efj = ef + (size_t)j * F;
    float h[64];
    #pragma unroll
    for (int n = 0; n < 64; ++n) h[n] = b1[n];
    for (int k = 0; k < F; ++k) {
        float ei = efi[k];
        float ej = efj[k];
        const float* wi = W1 + (size_t)k * 64;
        const float* wj = W1 + (size_t)(F + k) * 64;
        #pragma unroll
        for (int n = 0; n < 64; ++n) h[n] += ei * wi[n] + ej * wj[n];
    }
    float pr[32];
    mlp_tail_compute(h, pr, D, g1, be1, W2, b2, g2, be2, W3, b3);

    if (D == 16) {
        #pragma unroll
        for (int d = 0; d < 16; ++d) pp[threadIdx.x * 17 + d] = pr[d];
        __syncthreads();
        store_diag16_f32_256(pp, out, P);
    } else {
        if (p < P) {
            float* po = out + (size_t)p * D * D;
            for (int r = 0; r < D; ++r) {
                float dv = pr[r];
                for (int c = 0; c < D; ++c) po[r * D + c] = (r == c) ? dv : 0.f;
            }
        }
    }
}

// ---------------- Host side: derive ALL dims from in_sizes/out_size ----------------
struct Map { int ef, pi, pj, w1, b1, g1, be1, w2, b2, g2, be2, w3, b3; };

static bool validate_map(const Map& m, const int* s, int n_in, long out_size,
                         int* Fo, int* Eo, int* Do, int* Po) {
    if (n_in < 13) return false;
    if (s[m.b1] != 64 || s[m.g1] != 64 || s[m.be1] != 64) return false;
    if (s[m.b2] != 32 || s[m.g2] != 32 || s[m.be2] != 32) return false;
    if (s[m.w2] != 64 * 32) return false;
    long w1 = s[m.w1];
    if (w1 <= 0 || (w1 % 128) != 0) return false;       // W1 = (2F, 64)
    long F = w1 / 128;
    if (F <= 0) return false;
    int D = s[m.b3];
    if (D <= 0 || D > 32) return false;
    if (s[m.w3] != 32 * D) return false;
    long P = s[m.pi];
    if (P <= 0 || s[m.pj] != P) return false;
    long ef = s[m.ef];
    if (ef <= 0 || (ef % F) != 0) return false;
    long E = ef / F;
    if (out_size != P * D * D) return false;
    *Fo = (int)F; *Eo = (int)E; *Do = D; *Po = (int)P;
    return true;
}

extern "C" void kernel_launch(void* const* d_in, const int* in_sizes, int n_in,
                              void* d_out, int out_size, void* d_ws, size_t ws_size,
                              hipStream_t stream) {
    const Map pos   = {0, 1, 2, 3, 4, 5, 6, 7, 8, 9, 10, 11, 12};
    const Map alpha = {8, 11, 12, 0, 3, 9, 6, 1, 4, 10, 7, 2, 5};

    int F = 0, E = 0, D = 0, P = 0;
    Map m;
    if (validate_map(pos, in_sizes, n_in, (long)out_size, &F, &E, &D, &P)) {
        m = pos;
    } else if (validate_map(alpha, in_sizes, n_in, (long)out_size, &F, &E, &D, &P)) {
        m = alpha;
    } else {
        bad_map_marker<<<dim3(1), dim3(64), 0, stream>>>((float*)d_out);
        return;
    }

    const float* ef  = (const float*)d_in[m.ef];
    const int*   pi  = (const int*)d_in[m.pi];
    const int*   pj  = (const int*)d_in[m.pj];
    const float* W1  = (const float*)d_in[m.w1];
    const float* b1  = (const float*)d_in[m.b1];
    const float* g1  = (const float*)d_in[m.g1];
    const float* be1 = (const float*)d_in[m.be1];
    const float* W2  = (const float*)d_in[m.w2];
    const float* b2  = (const float*)d_in[m.b2];
    const float* g2  = (const float*)d_in[m.g2];
    const float* be2 = (const float*)d_in[m.be2];
    const float* W3  = (const float*)d_in[m.w3];
    const float* b3  = (const float*)d_in[m.b3];
    float* out = (float*)d_out;

    const size_t y_bytes = (size_t)E * 128 * 4;

    if (F == 128 && D == 16 && ws_size >= y_bytes) {
        float* Y = (float*)d_ws;
        precompute_y<<<dim3((E + 31) / 32), dim3(256), 0, stream>>>(ef, W1, b1, Y, E);
        sheaf_pairs<<<dim3((P + 255) / 256), dim3(256), 0, stream>>>(
            pi, pj, Y, g1, be1, W2, b2, g2, be2, W3, b3, out, P);
    } else {
        sheaf_generic<<<dim3((P + 255) / 256), dim3(256), 0, stream>>>(
            ef, pi, pj, W1, b1, g1, be1, W2, b2, g2, be2, W3, b3, out, P, F, D);
    }
}

// Round 7
// 382.210 us; speedup vs baseline: 1.8536x; 1.8536x over previous
//
#include <hip/hip_runtime.h>
#include <hip/hip_fp16.h>

// ---------------- Diagnostic marker: neither input mapping validated ----------------
__global__ void bad_map_marker(float* out) {
    if (threadIdx.x == 0 && blockIdx.x == 0) out[0] = 1.0e6f;
}

// ---------------- Tail: LN1(64)+ReLU -> L2(64,32) -> LN2+ReLU -> L3(32,D) ----------------
// Weight pointers may be LDS (broadcast reads) or global (fallback path).
__device__ __forceinline__ void mlp_tail_compute(float* h, float* pr, int D,
        const float* g1, const float* be1,
        const float* W2, const float* b2,
        const float* g2, const float* be2,
        const float* W3, const float* b3) {
    float s = 0.f, ss = 0.f;
    #pragma unroll
    for (int d = 0; d < 64; ++d) { s += h[d]; ss += h[d] * h[d]; }
    float mu  = s * (1.f / 64.f);
    float inv = rsqrtf(ss * (1.f / 64.f) - mu * mu + 1e-5f);
    #pragma unroll
    for (int d = 0; d < 64; ++d)
        h[d] = fmaxf((h[d] - mu) * inv * g1[d] + be1[d], 0.f);

    float a2[32];
    const float4* w2v = (const float4*)W2;
    #pragma unroll
    for (int n = 0; n < 32; ++n) a2[n] = b2[n];
    for (int k = 0; k < 64; ++k) {
        float hk = h[k];
        #pragma unroll
        for (int q = 0; q < 8; ++q) {
            float4 w = w2v[k * 8 + q];
            a2[4 * q + 0] += hk * w.x;
            a2[4 * q + 1] += hk * w.y;
            a2[4 * q + 2] += hk * w.z;
            a2[4 * q + 3] += hk * w.w;
        }
    }
    s = 0.f; ss = 0.f;
    #pragma unroll
    for (int n = 0; n < 32; ++n) { s += a2[n]; ss += a2[n] * a2[n]; }
    mu  = s * (1.f / 32.f);
    inv = rsqrtf(ss * (1.f / 32.f) - mu * mu + 1e-5f);
    #pragma unroll
    for (int n = 0; n < 32; ++n)
        a2[n] = fmaxf((a2[n] - mu) * inv * g2[n] + be2[n], 0.f);

    for (int d = 0; d < D; ++d) pr[d] = b3[d];
    for (int k = 0; k < 32; ++k) {
        float hk = a2[k];
        const float* wr = W3 + k * D;
        for (int d = 0; d < D; ++d) pr[d] += hk * wr[d];
    }
}

// Coalesced diag-embed epilogue, 256 pairs/block -> 16384 float4 chunks. Plain stores
// (measured: nt-stores +10us on this path).
__device__ __forceinline__ void store_diag16_f32_256(const float* pp, float* out, int P) {
    const int t = threadIdx.x;
    float4* outv = (float4*)out + (size_t)blockIdx.x * 16384;
    const int pbase = blockIdx.x * 256;
    #pragma unroll 8
    for (int it = 0; it < 64; ++it) {
        int g = it * 256 + t;
        int pl = g >> 6;
        int rem = g & 63;
        int d = rem >> 2;
        int c4 = rem & 3;
        float val = pp[pl * 17 + d];
        bool on = (d >> 2) == c4;
        float4 v;
        v.x = (on && (d & 3) == 0) ? val : 0.f;
        v.y = (on && (d & 3) == 1) ? val : 0.f;
        v.z = (on && (d & 3) == 2) ? val : 0.f;
        v.w = (on && (d & 3) == 3) ? val : 0.f;
        if (pbase + pl < P) outv[g] = v;
    }
}

// ---------------- Fast path stage 1 (F==128): tiled GEMM, Y[e][n] in FP16 ----------------
// R0/R4 structure (64 edges x 128 cols, thread: 4 edges x 8 cols). Only change:
// Y stored as fp16 -> 5 MB total (near L2-resident per XCD), gather bytes halved.
__global__ __launch_bounds__(256)
void precompute_y(const float* __restrict__ ef, const float* __restrict__ W1,
                  const float* __restrict__ b1, __half* __restrict__ Y, int E) {
    __shared__ __align__(16) float el[64 * 132];   // 33792 B
    const int t = threadIdx.x;
    const int ebase = blockIdx.x * 64;

    for (int idx = t; idx < 2048; idx += 256) {
        int er = idx >> 5, ec = idx & 31;
        if (ebase + er < E)
            *((float4*)(el + er * 132) + ec) =
                *((const float4*)(ef + (size_t)(ebase + er) * 128) + ec);
    }
    __syncthreads();

    const int cg = t & 15;
    const int eg = t >> 4;
    const int half_ = cg >> 3;
    const int col64 = (cg & 7) * 8;

    float acc[4][8];
    #pragma unroll
    for (int i = 0; i < 4; ++i)
        #pragma unroll
        for (int c = 0; c < 8; ++c) acc[i][c] = 0.f;

    const float* wbase = W1 + (size_t)half_ * 128 * 64 + col64;
    #pragma unroll 4
    for (int k = 0; k < 128; ++k) {
        float4 w0 = *(const float4*)(wbase + (size_t)k * 64);
        float4 w1 = *(const float4*)(wbase + (size_t)k * 64 + 4);
        float wv[8] = {w0.x, w0.y, w0.z, w0.w, w1.x, w1.y, w1.z, w1.w};
        #pragma unroll
        for (int i = 0; i < 4; ++i) {
            float a = el[(eg * 4 + i) * 132 + k];
            #pragma unroll
            for (int c = 0; c < 8; ++c) acc[i][c] += a * wv[c];
        }
    }

    float bb[8];
    #pragma unroll
    for (int c = 0; c < 8; ++c) bb[c] = (half_ == 0) ? b1[col64 + c] : 0.f;
    #pragma unroll
    for (int i = 0; i < 4; ++i) {
        int e = ebase + eg * 4 + i;
        if (e < E) {
            __half* dst = Y + (size_t)e * 128 + half_ * 64 + col64;
            __half2 hv[4];
            #pragma unroll
            for (int c = 0; c < 4; ++c)
                hv[c] = __floats2half2_rn(acc[i][2 * c] + bb[2 * c],
                                          acc[i][2 * c + 1] + bb[2 * c + 1]);
            *(float4*)dst = *(float4*)hv;   // 8 halfs = 16 B, aligned
        }
    }
}

// ---------------- Fast path stage 2: 1 thread/pair, fp16 Y gather, weights in LDS ----------------
__global__ __launch_bounds__(256)
void sheaf_pairs(const int* __restrict__ pi, const int* __restrict__ pj,
                 const __half* __restrict__ Y,
                 const float* __restrict__ g1, const float* __restrict__ be1,
                 const float* __restrict__ W2, const float* __restrict__ b2,
                 const float* __restrict__ g2, const float* __restrict__ be2,
                 const float* __restrict__ W3, const float* __restrict__ b3,
                 float* __restrict__ out, int P) {
    __shared__ float pp[256 * 17];
    __shared__ __align__(16) float w2s[64 * 32];
    __shared__ __align__(16) float w3s[32 * 16];
    __shared__ float g1s[64], be1s[64], b2s[32], g2s[32], be2s[32], b3s[16];

    const int t = threadIdx.x;
    int p = blockIdx.x * 256 + t;
    int pc = p < P ? p : P - 1;
    int i = pi[pc], j = pj[pc];

    // Gather: 128 B per row-half (8 x 16B chunks), fp16.
    const float4* y1 = (const float4*)(Y + (size_t)i * 128);
    const float4* y2 = (const float4*)(Y + (size_t)j * 128 + 64);
    float4 ra[8], rb[8];
    #pragma unroll
    for (int q = 0; q < 8; ++q) { ra[q] = y1[q]; rb[q] = y2[q]; }

    // Stage all MLP-tail weights into LDS (once per block) — overlaps gather latency.
    {
        const float4* s2 = (const float4*)W2;      // 512 float4
        float4* d2 = (float4*)w2s;
        d2[t]       = s2[t];
        d2[t + 256] = s2[t + 256];
        if (t < 128) ((float4*)w3s)[t] = ((const float4*)W3)[t];   // 128 float4
        if (t < 64)                 { g1s[t] = g1[t]; be1s[t] = be1[t]; }
        else if (t < 96)            b2s[t - 64]   = b2[t - 64];
        else if (t < 128)           g2s[t - 96]   = g2[t - 96];
        else if (t < 160)           be2s[t - 128] = be2[t - 128];
        else if (t < 176)           b3s[t - 160]  = b3[t - 160];
    }

    float h[64];
    #pragma unroll
    for (int q = 0; q < 8; ++q) {
        const __half2* ha = (const __half2*)&ra[q];
        const __half2* hb = (const __half2*)&rb[q];
        #pragma unroll
        for (int u = 0; u < 4; ++u) {
            float2 fa = __half22float2(ha[u]);
            float2 fb = __half22float2(hb[u]);
            h[8 * q + 2 * u + 0] = fa.x + fb.x;
            h[8 * q + 2 * u + 1] = fa.y + fb.y;
        }
    }
    __syncthreads();

    float pr[16];
    mlp_tail_compute(h, pr, 16, g1s, be1s, w2s, b2s, g2s, be2s, w3s, b3s);
    #pragma unroll
    for (int d = 0; d < 16; ++d) pp[t * 17 + d] = pr[d];
    __syncthreads();
    store_diag16_f32_256(pp, out, P);
}

// ---------------- Generic fallback: runtime F, D (<=32), all fp32 ----------------
__global__ __launch_bounds__(256)
void sheaf_generic(const float* __restrict__ ef,
                   const int* __restrict__ pi, const int* __restrict__ pj,
                   const float* __restrict__ W1, const float* __restrict__ b1,
                   const float* __restrict__ g1, const float* __restrict__ be1,
                   const float* __restrict__ W2, const float* __restrict__ b2,
                   const float* __restrict__ g2, const float* __restrict__ be2,
                   const float* __restrict__ W3, const float* __restrict__ b3,
                   float* __restrict__ out, int P, int F, int D) {
    __shared__ float pp[256 * 17];
    int p = blockIdx.x * 256 + threadIdx.x;
    int pc = p < P ? p : P - 1;
    int i = pi[pc], j = pj[pc];
    const float* efi = ef + (size_t)i * F;
    const float* efj = ef + (size_t)j * F;
    float h[64];
    #pragma unroll
    for (int n = 0; n < 64; ++n) h[n] = b1[n];
    for (int k = 0; k < F; ++k) {
        float ei = efi[k];
        float ej = efj[k];
        const float* wi = W1 + (size_t)k * 64;
        const float* wj = W1 + (size_t)(F + k) * 64;
        #pragma unroll
        for (int n = 0; n < 64; ++n) h[n] += ei * wi[n] + ej * wj[n];
    }
    float pr[32];
    mlp_tail_compute(h, pr, D, g1, be1, W2, b2, g2, be2, W3, b3);

    if (D == 16) {
        #pragma unroll
        for (int d = 0; d < 16; ++d) pp[threadIdx.x * 17 + d] = pr[d];
        __syncthreads();
        store_diag16_f32_256(pp, out, P);
    } else {
        if (p < P) {
            float* po = out + (size_t)p * D * D;
            for (int r = 0; r < D; ++r) {
                float dv = pr[r];
                for (int c = 0; c < D; ++c) po[r * D + c] = (r == c) ? dv : 0.f;
            }
        }
    }
}

// ---------------- Host side: derive ALL dims from in_sizes/out_size ----------------
struct Map { int ef, pi, pj, w1, b1, g1, be1, w2, b2, g2, be2, w3, b3; };

static bool validate_map(const Map& m, const int* s, int n_in, long out_size,
                         int* Fo, int* Eo, int* Do, int* Po) {
    if (n_in < 13) return false;
    if (s[m.b1] != 64 || s[m.g1] != 64 || s[m.be1] != 64) return false;
    if (s[m.b2] != 32 || s[m.g2] != 32 || s[m.be2] != 32) return false;
    if (s[m.w2] != 64 * 32) return false;
    long w1 = s[m.w1];
    if (w1 <= 0 || (w1 % 128) != 0) return false;       // W1 = (2F, 64)
    long F = w1 / 128;
    if (F <= 0) return false;
    int D = s[m.b3];
    if (D <= 0 || D > 32) return false;
    if (s[m.w3] != 32 * D) return false;
    long P = s[m.pi];
    if (P <= 0 || s[m.pj] != P) return false;
    long ef = s[m.ef];
    if (ef <= 0 || (ef % F) != 0) return false;
    long E = ef / F;
    if (out_size != P * D * D) return false;
    *Fo = (int)F; *Eo = (int)E; *Do = D; *Po = (int)P;
    return true;
}

extern "C" void kernel_launch(void* const* d_in, const int* in_sizes, int n_in,
                              void* d_out, int out_size, void* d_ws, size_t ws_size,
                              hipStream_t stream) {
    const Map pos   = {0, 1, 2, 3, 4, 5, 6, 7, 8, 9, 10, 11, 12};
    const Map alpha = {8, 11, 12, 0, 3, 9, 6, 1, 4, 10, 7, 2, 5};

    int F = 0, E = 0, D = 0, P = 0;
    Map m;
    if (validate_map(pos, in_sizes, n_in, (long)out_size, &F, &E, &D, &P)) {
        m = pos;
    } else if (validate_map(alpha, in_sizes, n_in, (long)out_size, &F, &E, &D, &P)) {
        m = alpha;
    } else {
        bad_map_marker<<<dim3(1), dim3(64), 0, stream>>>((float*)d_out);
        return;
    }

    const float* ef  = (const float*)d_in[m.ef];
    const int*   pi  = (const int*)d_in[m.pi];
    const int*   pj  = (const int*)d_in[m.pj];
    const float* W1  = (const float*)d_in[m.w1];
    const float* b1  = (const float*)d_in[m.b1];
    const float* g1  = (const float*)d_in[m.g1];
    const float* be1 = (const float*)d_in[m.be1];
    const float* W2  = (const float*)d_in[m.w2];
    const float* b2  = (const float*)d_in[m.b2];
    const float* g2  = (const float*)d_in[m.g2];
    const float* be2 = (const float*)d_in[m.be2];
    const float* W3  = (const float*)d_in[m.w3];
    const float* b3  = (const float*)d_in[m.b3];
    float* out = (float*)d_out;

    const size_t y_bytes = (size_t)E * 128 * sizeof(__half);

    if (F == 128 && D == 16 && ws_size >= y_bytes) {
        __half* Y = (__half*)d_ws;
        precompute_y<<<dim3((E + 63) / 64), dim3(256), 0, stream>>>(ef, W1, b1, Y, E);
        sheaf_pairs<<<dim3((P + 255) / 256), dim3(256), 0, stream>>>(
            pi, pj, Y, g1, be1, W2, b2, g2, be2, W3, b3, out, P);
    } else {
        sheaf_generic<<<dim3((P + 255) / 256), dim3(256), 0, stream>>>(
            ef, pi, pj, W1, b1, g1, be1, W2, b2, g2, be2, W3, b3, out, P, F, D);
    }
}